// Round 11
// baseline (438.440 us; speedup 1.0000x reference)
//
#include <hip/hip_runtime.h>
#include <stdint.h>

// PyramidAttention gfx950 — round 24: counted-vmcnt barrier in k_attn128.
// R23 ledger: 5354 cyc/chunk/SIMD = 2095 MFMA + ~950 ds + ~2300 unexplained =
// the __syncthreads vmcnt(0) drain (R[ch] 36KB issued one phase earlier must
// land before ANY wave passes). Fix, isolated on the winning structure:
// B tri-buffered (staged 3 ahead), issue order R-then-B, barrier becomes
// s_waitcnt vmcnt(8) lgkmcnt(0); s_barrier. Per-wave ledger: newer-than-R[ch]
// = B[ch+2]+R[ch+1]+B[ch+3] >= 8 instrs for every wave -> vmcnt(8) provably
// drains R[ch] (Z(ch)) and B[ch+1] (S(ch+1)) while keeping R[ch+1]+B[ch+3]
// in flight across the barrier (full-phase DMA cover). Tail (last 4 iters)
// uses vmcnt(0). LDS 124->142KB (still 1 blk/CU; registers bind).
// Everything else byte-identical to R23 (435us best).

typedef __attribute__((ext_vector_type(8))) short bf16x8;
typedef __attribute__((ext_vector_type(4))) float f32x4;
typedef unsigned short ushort_t;

#define L_TOT  13326
#define NCHT   417
#define NPIX   4096
#define BCHUNK_E 9216  // 32 cols * 288 k
#define RCHUNK_E 18432 // 576 cols * 32 l
#define LOG2E10 14.4269504f   // 10*log2(e)
#define CT 256         // k_convref l-tile

__device__ __forceinline__ float cubw(float d) {
  d = fabsf(d);
  if (d <= 1.f) return (1.25f * d - 2.25f) * d * d + 1.f;          // A=-0.75
  if (d < 2.f)  return ((-0.75f * d + 3.75f) * d - 6.f) * d + 3.f;
  return 0.f;
}

__device__ __forceinline__ void decode_l(int l, int& S, int& off) {
  if (l < 4096)       { S = 64; off = 0; }
  else if (l < 7345)  { S = 57; off = 4096; }
  else if (l < 9946)  { S = 51; off = 7345; }
  else if (l < 11882) { S = 44; off = 9946; }
  else                { S = 38; off = 11882; }
}

__device__ __forceinline__ ushort_t f2bf(float f) {
  union { float f; uint32_t u; } v; v.f = f;
  uint32_t r = (v.u + 0x7fffu + ((v.u >> 16) & 1u)) >> 16;  // RNE
  return (ushort_t)r;
}

__device__ __forceinline__ float preluf(float x, float a) { return x >= 0.f ? x : a * x; }

__device__ __forceinline__ void gll16(const ushort_t* g, ushort_t* l) {
  __builtin_amdgcn_global_load_lds(
      (const __attribute__((address_space(1))) unsigned int*)g,
      (__attribute__((address_space(3))) unsigned int*)l, 16, 0, 0);
}

// ---------------- K2: bicubic + conv1x1 + prelu fused ----------------
__global__ void k_convref(const float* __restrict__ inref,
                          const float* __restrict__ Wm, const float* __restrict__ bm,
                          const float* __restrict__ Wa, const float* __restrict__ ba,
                          const float* __restrict__ ap,
                          float* __restrict__ mref, float* __restrict__ aref) {
  __shared__ float T[64][CT];
  __shared__ float Wy[CT][5], Wx[CT][5];
  __shared__ int   IY[CT], IX[CT];
  int blk = blockIdx.x;
  int oh = blk & 1; int lt = (blk >> 1) % 53; int b = blk / 106;
  int l0 = lt * CT;
  int tid = threadIdx.x;
  float a = ap[0];
  {
    int gl = l0 + tid;
    if (gl < L_TOT) {
      int S, off; decode_l(gl, S, off);
      int li = gl - off; int ly = li / S, lx = li % S;
      if (S == 64) {
        IY[tid] = -1; IX[tid] = ly * 64 + lx;
      } else {
        float sc = (float)(63.0 / (double)(S - 1));
        float sy = (float)ly * sc, sx = (float)lx * sc;
        int iy = (int)floorf(sy), ix = (int)floorf(sx);
        float fy = sy - (float)iy, fx = sx - (float)ix;
        IY[tid] = iy; IX[tid] = ix;
        Wy[tid][0] = cubw(fy + 1.f); Wy[tid][1] = cubw(fy);
        Wy[tid][2] = cubw(1.f - fy); Wy[tid][3] = cubw(2.f - fy);
        Wx[tid][0] = cubw(fx + 1.f); Wx[tid][1] = cubw(fx);
        Wx[tid][2] = cubw(1.f - fx); Wx[tid][3] = cubw(2.f - fx);
      }
    }
  }
  __syncthreads();
  for (int i = tid; i < 64 * CT; i += 256) {
    int c = i >> 8; int l2 = i & 255;
    int gl = l0 + l2;
    float val = 0.f;
    if (gl < L_TOT) {
      const float* img = inref + (size_t)(b * 64 + c) * 4096;
      int iy = IY[l2];
      if (iy == -1) {
        val = img[IX[l2]];
      } else {
        int ix = IX[l2];
        #pragma unroll
        for (int t = 0; t < 4; ++t) {
          int ty = iy - 1 + t; ty = ty < 0 ? 0 : (ty > 63 ? 63 : ty);
          float rv = 0.f;
          #pragma unroll
          for (int u = 0; u < 4; ++u) {
            int tx = ix - 1 + u; tx = tx < 0 ? 0 : (tx > 63 ? 63 : tx);
            rv += Wx[l2][u] * img[ty * 64 + tx];
          }
          val += Wy[l2][t] * rv;
        }
      }
    }
    T[c][l2] = val;
  }
  __syncthreads();
  int gl = l0 + tid;
  if (gl >= L_TOT) return;
  for (int oc = oh * 48; oc < oh * 48 + 48; ++oc) {
    const float* Wrow; float s;
    if (oc < 32) { Wrow = Wm + oc * 64; s = bm[oc]; }
    else         { Wrow = Wa + (oc - 32) * 64; s = ba[oc - 32]; }
    #pragma unroll 8
    for (int c = 0; c < 64; ++c) s += Wrow[c] * T[c][tid];
    s = preluf(s, a);
    if (oc < 32) mref[(size_t)(b * 32 + oc) * L_TOT + gl] = s;
    else         aref[(size_t)(b * 64 + oc - 32) * L_TOT + gl] = s;
  }
}

// ---------------- K3: match_base = prelu(Wb@input+bb) ----------------
__global__ void k_mb(const float* __restrict__ input, const float* __restrict__ Wb,
                     const float* __restrict__ bb, const float* __restrict__ ap,
                     float* __restrict__ mbb, int n) {
  int idx = blockIdx.x * 256 + threadIdx.x;
  if (idx >= n) return;                      // n = 2*32*NPIX
  int p = idx % NPIX; int cm = (idx / NPIX) % 32; int b = idx / (32 * NPIX);
  float a = ap[0];
  float acc = bb[cm];
  for (int c = 0; c < 64; ++c) acc += Wb[cm * 64 + c] * input[(size_t)(b * 64 + c) * NPIX + p];
  mbb[(size_t)(b * 32 + cm) * NPIX + p] = preluf(acc, a);
}

// ---------------- K4s1: ssq U ssqA ----------------
__global__ void k_stage1(const float* __restrict__ mref, const float* __restrict__ mbb,
                         float* __restrict__ ssq, float* __restrict__ ssqA, int n) {
  int idx = blockIdx.x * 256 + threadIdx.x;
  if (idx >= n) return;                      // n = 2*L_TOT + 2*NPIX
  if (idx < 2 * L_TOT) {
    int l = idx % L_TOT; int b = idx / L_TOT;
    float s = 0.f;
    for (int c = 0; c < 32; ++c) { float v = mref[(size_t)(b * 32 + c) * L_TOT + l]; s += v * v; }
    ssq[idx] = s;
  } else {
    int j = idx - 2 * L_TOT;
    int p = j % NPIX; int b = j / NPIX;
    float s = 0.f;
    for (int c = 0; c < 32; ++c) { float v = mbb[(size_t)(b * 32 + c) * NPIX + p]; s += v * v; }
    ssqA[j] = s;
  }
}

// ---------------- K4s2: invn U Mlog ----------------
__global__ void k_stage2(const float* __restrict__ ssq, const float* __restrict__ ssqA,
                         float* __restrict__ invn, float* __restrict__ Mlog, int n) {
  int idx = blockIdx.x * 256 + threadIdx.x;
  if (idx >= n) return;                      // n = 2*L_TOT + 2*NPIX
  if (idx < 2 * L_TOT) {
    int l = idx % L_TOT; int b = idx / L_TOT;
    int S, off; decode_l(l, S, off);
    int li = l - off; int ly = li / S, lx = li % S;
    float acc = 0.f;
    for (int dy = -1; dy <= 1; ++dy) {
      int ny = ly + dy; if (ny < 0 || ny >= S) continue;
      for (int dx = -1; dx <= 1; ++dx) {
        int nx = lx + dx; if (nx < 0 || nx >= S) continue;
        acc += ssq[(size_t)b * L_TOT + off + ny * S + nx];
      }
    }
    float nrm = sqrtf(acc); nrm = fmaxf(nrm, 1e-4f);
    invn[idx] = 1.f / nrm;
  } else {
    int j = idx - 2 * L_TOT;
    int p = j % NPIX; int b = j / NPIX;
    int y = p / 64, x = p % 64;
    float acc = 0.f;
    for (int dy = -1; dy <= 1; ++dy) {
      int ny = y + dy; if (ny < 0 || ny >= 64) continue;
      for (int dx = -1; dx <= 1; ++dx) {
        int nx = x + dx; if (nx < 0 || nx >= 64) continue;
        acc += ssqA[(size_t)b * NPIX + ny * 64 + nx];
      }
    }
    float qn = sqrtf(acc);
    float m = fmaxf(0.7f * qn, qn - 7.f);
    Mlog[j] = LOG2E10 * m;
  }
}

// ---------------- K5/6/7 merged: Bs U Am U Rs packing, vec8 ----------------
#define N_BS (2 * NCHT * 1152)
#define N_AIM (2 * NPIX * 36)
#define N_RS (2 * NCHT * 576 * 4)
__global__ void k_pack(const float* __restrict__ mref, const float* __restrict__ invn,
                       const float* __restrict__ mbb, const float* __restrict__ aref,
                       ushort_t* __restrict__ Bs, ushort_t* __restrict__ Am,
                       ushort_t* __restrict__ Rs, int n) {
  int idx = blockIdx.x * 256 + threadIdx.x;
  if (idx >= n) return;
  ushort_t v[8];
  if (idx < N_BS) {
    int segp = idx % 36; int col = (idx / 36) % 32;
    int ch = (idx / 1152) % NCHT; int b = idx / (1152 * NCHT);
    int segl = (segp & ~3) | ((segp & 3) ^ ((col >> 1) & 3));
    int l = ch * 32 + col;
    if (l < L_TOT) {
      int S, off; decode_l(l, S, off);
      int li = l - off; int ly = li / S, lx = li % S;
      float iv = invn[(size_t)b * L_TOT + l];
      #pragma unroll
      for (int e = 0; e < 8; ++e) {
        int k = segl * 8 + e;
        int c = k / 9; int r = k % 9; int dy = r / 3 - 1, dx = r % 3 - 1;
        int ny = ly + dy, nx = lx + dx;
        float val = 0.f;
        if (ny >= 0 && ny < S && nx >= 0 && nx < S)
          val = mref[(size_t)(b * 32 + c) * L_TOT + off + ny * S + nx] * iv;
        v[e] = f2bf(val);
      }
    } else {
      #pragma unroll
      for (int e = 0; e < 8; ++e) v[e] = 0;
    }
    *(uint4*)(Bs + ((size_t)(b * NCHT + ch) * BCHUNK_E + col * 288 + segp * 8)) = *(const uint4*)v;
  } else if (idx < N_BS + N_AIM) {
    int j = idx - N_BS;
    int k8 = j % 36; int p = (j / 36) % NPIX; int b = j / (36 * NPIX);
    int y = p / 64, x = p % 64;
    #pragma unroll
    for (int e = 0; e < 8; ++e) {
      int k = k8 * 8 + e;
      int c = k / 9; int r = k % 9; int dy = r / 3 - 1, dx = r % 3 - 1;
      int ny = y + dy, nx = x + dx;
      float val = 0.f;
      if (ny >= 0 && ny < 64 && nx >= 0 && nx < 64)
        val = mbb[(size_t)(b * 32 + c) * NPIX + ny * 64 + nx];
      v[e] = f2bf(val);
    }
    *(uint4*)(Am + ((size_t)(b * NPIX + p) * 288 + k8 * 8)) = *(const uint4*)v;
  } else {
    int j = idx - N_BS - N_AIM;
    int phys = j & 3; int q = j >> 2;
    int col = q % 576; q /= 576;
    int ch = q % NCHT; int b = q / NCHT;
    int c = col / 9; int r = col % 9; int dy = r / 3 - 1, dx = r % 3 - 1;
    int seg = phys ^ ((col >> 1) & 3);
    int lbase = ch * 32 + seg * 8;
    #pragma unroll
    for (int e = 0; e < 8; ++e) {
      int l = lbase + e;
      float val = 0.f;
      if (l < L_TOT) {
        int S, off; decode_l(l, S, off);
        int li = l - off; int ly = li / S, lx = li % S;
        int ny = ly + dy, nx = lx + dx;
        if (ny >= 0 && ny < S && nx >= 0 && nx < S)
          val = aref[(size_t)(b * 64 + c) * L_TOT + off + ny * S + nx];
      }
      v[e] = f2bf(val);
    }
    *(uint4*)(Rs + ((size_t)(b * NCHT + ch) * RCHUNK_E + col * 32 + phys * 8)) = *(const uint4*)v;
  }
}

// ---------------- K8a: M=64 flash attention (R13 proven fallback) ----------------
__global__ __launch_bounds__(512, 2) void k_attn64(const ushort_t* __restrict__ Am,
                                                   const ushort_t* __restrict__ Bs,
                                                   const ushort_t* __restrict__ Rs,
                                                   const float* __restrict__ Mlog,
                                                   float* __restrict__ Og,
                                                   float* __restrict__ Ol) {
  __shared__ ushort_t Rl[3][RCHUNK_E];
  __shared__ ushort_t Bl[2][BCHUNK_E];
  __shared__ ushort_t Pl[2][2048];
  int tid = threadIdx.x;
  int xcd = blockIdx.x & 7; int slot = blockIdx.x >> 3;
  int group = xcd >> 1;
  int spl = group & 1; int b = group >> 1;
  int tile = slot * 2 + (xcd & 1);
  int p0 = tile * 64;
  int wave = tid >> 6, lane = tid & 63, quad = lane >> 4, ln = lane & 15;
  int rbS = wave & 3, cbh = wave >> 2;
  int g = wave & 3, zrh = wave >> 2;
  int c0 = spl ? 209 : 0, c1 = spl ? NCHT : 209;

  bf16x8 af[9];
  {
    const ushort_t* arow = Am + (size_t)(b * NPIX + p0 + rbS * 16 + ln) * 288;
    #pragma unroll
    for (int kk = 0; kk < 9; ++kk) af[kk] = *(const bf16x8*)(arow + kk * 32 + quad * 8);
  }
  float mlg[4];
  #pragma unroll
  for (int r = 0; r < 4; ++r)
    mlg[r] = Mlog[(size_t)b * NPIX + p0 + rbS * 16 + quad * 4 + r];

  f32x4 acc[2][9];
  #pragma unroll
  for (int h = 0; h < 2; ++h)
    #pragma unroll
    for (int t = 0; t < 9; ++t) { acc[h][t][0] = acc[h][t][1] = acc[h][t][2] = acc[h][t][3] = 0.f; }
  float psum[4] = {0.f, 0.f, 0.f, 0.f};

  const ushort_t* RsB = Rs + (size_t)b * NCHT * RCHUNK_E + lane * 8;
  const ushort_t* BsB = Bs + (size_t)b * NCHT * BCHUNK_E + lane * 8;

  {
    const ushort_t* sB0 = BsB + (size_t)c0 * BCHUNK_E;
    ushort_t* dB0 = Bl[c0 & 1];
    #pragma unroll
    for (int u = wave; u < 18; u += 8) gll16(sB0 + u * 512, dB0 + u * 512);
    const ushort_t* sB1 = BsB + (size_t)(c0 + 1) * BCHUNK_E;
    ushort_t* dB1 = Bl[(c0 + 1) & 1];
    #pragma unroll
    for (int u = wave; u < 18; u += 8) gll16(sB1 + u * 512, dB1 + u * 512);
    const ushort_t* sR = RsB + (size_t)c0 * RCHUNK_E;
    ushort_t* dR = Rl[c0 % 3];
    #pragma unroll
    for (int u = wave; u < 36; u += 8) gll16(sR + u * 512, dR + u * 512);
  }
  __syncthreads();

  int col32 = cbh * 16 + ln;
  int bswz = (col32 >> 1) & 3;
  int rpar = c0 % 3;
  for (int ch = c0; ch < c1; ++ch) {
    int par = ch & 1;
    int rnext = rpar == 2 ? 0 : rpar + 1;
    f32x4 sa, sb;
    sa[0] = sa[1] = sa[2] = sa[3] = 0.f;
    sb[0] = sb[1] = sb[2] = sb[3] = 0.f;
    #pragma unroll
    for (int kk = 0; kk < 9; ++kk) {
      int segp = kk * 4 + (quad ^ bswz);
      bf16x8 bf = *(const bf16x8*)&Bl[par][col32 * 288 + segp * 8];
      if (kk == 4 || kk == 5 || kk == 6 || kk == 7)
        sb = __builtin_amdgcn_mfma_f32_16x16x32_bf16(af[kk], bf, sb, 0, 0, 0);
      else
        sa = __builtin_amdgcn_mfma_f32_16x16x32_bf16(af[kk], bf, sa, 0, 0, 0);
    }
    int colw = ch * 32 + col32;
    bool valid = colw < L_TOT;
    #pragma unroll
    for (int r = 0; r < 4; ++r) {
      float sv = sa[r] + sb[r];
      float pv = valid ? exp2f(fmaf(sv, LOG2E10, -mlg[r])) : 0.f;
      int row = rbS * 16 + quad * 4 + r;
      int seg = cbh * 2 + (ln >> 3);
      int swz = seg ^ ((row >> 1) & 3);
      Pl[par][row * 32 + swz * 8 + (ln & 7)] = f2bf(pv);
      psum[r] += pv;
    }
    __syncthreads();
    if (ch + 2 < c1) {
      const ushort_t* sB = BsB + (size_t)(ch + 2) * BCHUNK_E;
      ushort_t* dB = Bl[par];
      #pragma unroll
      for (int u = wave; u < 18; u += 8) gll16(sB + u * 512, dB + u * 512);
    }
    if (ch + 1 < c1) {
      const ushort_t* sR = RsB + (size_t)(ch + 1) * RCHUNK_E;
      ushort_t* dR = Rl[rnext];
      #pragma unroll
      for (int u = wave; u < 36; u += 8) gll16(sR + u * 512, dR + u * 512);
    }
    bf16x8 pf0, pf1;
    {
      int sw = quad ^ ((ln >> 1) & 3);
      pf0 = *(const bf16x8*)&Pl[par][(zrh * 32 + ln) * 32 + sw * 8];
      pf1 = *(const bf16x8*)&Pl[par][(zrh * 32 + 16 + ln) * 32 + sw * 8];
    }
    #pragma unroll
    for (int t = 0; t < 9; ++t) {
      int col = g * 144 + t * 16 + ln;
      int swz = quad ^ ((col >> 1) & 3);
      bf16x8 rf = *(const bf16x8*)&Rl[rpar][col * 32 + swz * 8];
      acc[0][t] = __builtin_amdgcn_mfma_f32_16x16x32_bf16(pf0, rf, acc[0][t], 0, 0, 0);
      acc[1][t] = __builtin_amdgcn_mfma_f32_16x16x32_bf16(pf1, rf, acc[1][t], 0, 0, 0);
    }
    rpar = rnext;
  }

  #pragma unroll
  for (int m = 1; m <= 8; m <<= 1)
    #pragma unroll
    for (int r = 0; r < 4; ++r) psum[r] += __shfl_xor(psum[r], m);
  int sb2 = spl * 2 + b;
  if (ln == 0) {
    #pragma unroll
    for (int r = 0; r < 4; ++r) {
      int row = p0 + rbS * 16 + quad * 4 + r;
      Ol[(size_t)(sb2 * 2 + cbh) * NPIX + row] = psum[r];
    }
  }
  #pragma unroll
  for (int h = 0; h < 2; ++h)
    #pragma unroll
    for (int t = 0; t < 9; ++t) {
      int colg = g * 144 + t * 16 + ln;
      #pragma unroll
      for (int r = 0; r < 4; ++r) {
        int row = p0 + zrh * 32 + h * 16 + quad * 4 + r;
        Og[((size_t)sb2 * NPIX + row) * 576 + colg] = acc[h][t][r];
      }
    }
}

// ---------------- K8b: M=128 flash attention, counted-vmcnt barrier ----------------
// R18 structure; B tri-buffered (staged 3 ahead), issue R[ch+1] then B[ch+3],
// barrier = s_waitcnt vmcnt(8) lgkmcnt(0); s_barrier (steady state) / vmcnt(0)
// (last 4 iters). Per-wave gll16 counts: R: w0-3=5,w4-7=4; B: w0-1=3,w2-7=2.
// newer-than-R[ch] at iter-ch barrier = B[ch+2]+R[ch+1]+B[ch+3] >= 8 for all
// waves -> vmcnt(8) drains R[ch] (Z(ch) dep) and B[ch+1] (S(ch+1) dep).
__global__ __launch_bounds__(512, 2) void k_attn128(const ushort_t* __restrict__ Am,
                                                    const ushort_t* __restrict__ Bs,
                                                    const ushort_t* __restrict__ Rs,
                                                    const float* __restrict__ Mlog,
                                                    float* __restrict__ Og,
                                                    float* __restrict__ Ol) {
  __shared__ ushort_t Rl[2][RCHUNK_E];   // 73728 B
  __shared__ ushort_t Bl[3][BCHUNK_E];   // 55296 B (tribuf)
  __shared__ ushort_t Pl[2][4096];       // 16384 B: dbuf P tile 128x32 (swizzled)
  int tid = threadIdx.x;
  int xcd = blockIdx.x & 7; int slot = blockIdx.x >> 3;
  int spl = xcd >> 1; int b = xcd & 1;
  int p0 = slot * 128;
  int wave = tid >> 6, lane = tid & 63, quad = lane >> 4, ln = lane & 15;
  int rb = wave;                          // S role: one 16-row block
  int g = wave & 3, zrh = wave >> 2;      // Z role
  int c0 = (spl * NCHT) >> 2;             // 0,104,208,312 (even)
  int c1 = ((spl + 1) * NCHT) >> 2;       // 104,208,312,417

  bf16x8 af[9];
  {
    const ushort_t* arow = Am + (size_t)(b * NPIX + p0 + rb * 16 + ln) * 288;
    #pragma unroll
    for (int kk = 0; kk < 9; ++kk) af[kk] = *(const bf16x8*)(arow + kk * 32 + quad * 8);
  }
  float mlg[4], psum[4];
  #pragma unroll
  for (int r = 0; r < 4; ++r) {
    mlg[r] = Mlog[(size_t)b * NPIX + p0 + rb * 16 + quad * 4 + r];
    psum[r] = 0.f;
  }
  f32x4 acc[4][9];
  #pragma unroll
  for (int j = 0; j < 4; ++j)
    #pragma unroll
    for (int t = 0; t < 9; ++t) { acc[j][t][0] = acc[j][t][1] = acc[j][t][2] = acc[j][t][3] = 0.f; }

  const ushort_t* RsB = Rs + (size_t)b * NCHT * RCHUNK_E + lane * 8;
  const ushort_t* BsB = Bs + (size_t)b * NCHT * BCHUNK_E + lane * 8;

  auto stageB = [&](int chunk, int sl) {
    const ushort_t* s = BsB + (size_t)chunk * BCHUNK_E;
    ushort_t* d = Bl[sl];
    #pragma unroll
    for (int u = wave; u < 18; u += 8) gll16(s + u * 512, d + u * 512);
  };
  auto stageR = [&](int chunk, int sl) {
    const ushort_t* s = RsB + (size_t)chunk * RCHUNK_E;
    ushort_t* d = Rl[sl];
    #pragma unroll
    for (int u = wave; u < 36; u += 8) gll16(s + u * 512, d + u * 512);
  };

  int bswz = (ln >> 1) & 3;               // ((cb*16+ln)>>1)&3 is cb-invariant
  int psw = quad ^ ((ln >> 1) & 3);

  // prologue: B[c0..c0+2] into tribuf slots, R[c0]; full drain.
  int b0 = c0 % 3;
  stageB(c0, b0);
  stageB(c0 + 1, b0 == 2 ? 0 : b0 + 1);
  stageB(c0 + 2, b0 == 0 ? 2 : b0 - 1);   // (c0+2)%3
  stageR(c0, 0);
  __syncthreads();

  int b3 = b0;                            // slot of B[ch] at loop iter ch
  for (int ch = c0; ch < c1; ++ch) {
    int par = ch & 1;
    // ---- S(ch): rows rb*16..+16, cols 0..31 (both halves), from Bl[b3] ----
    f32x4 sA0, sB0, sA1, sB1;
    sA0[0]=sA0[1]=sA0[2]=sA0[3]=0.f; sB0[0]=sB0[1]=sB0[2]=sB0[3]=0.f;
    sA1[0]=sA1[1]=sA1[2]=sA1[3]=0.f; sB1[0]=sB1[1]=sB1[2]=sB1[3]=0.f;
    #pragma unroll
    for (int kk = 0; kk < 9; ++kk) {
      int segp = kk * 4 + (quad ^ bswz);
      bf16x8 bf0 = *(const bf16x8*)&Bl[b3][(ln) * 288 + segp * 8];
      bf16x8 bf1 = *(const bf16x8*)&Bl[b3][(16 + ln) * 288 + segp * 8];
      if (kk >= 4 && kk <= 7) {
        sB0 = __builtin_amdgcn_mfma_f32_16x16x32_bf16(af[kk], bf0, sB0, 0, 0, 0);
        sB1 = __builtin_amdgcn_mfma_f32_16x16x32_bf16(af[kk], bf1, sB1, 0, 0, 0);
      } else {
        sA0 = __builtin_amdgcn_mfma_f32_16x16x32_bf16(af[kk], bf0, sA0, 0, 0, 0);
        sA1 = __builtin_amdgcn_mfma_f32_16x16x32_bf16(af[kk], bf1, sA1, 0, 0, 0);
      }
    }
    bool valid0 = ch * 32 + ln < L_TOT;
    bool valid1 = ch * 32 + 16 + ln < L_TOT;
    #pragma unroll
    for (int r = 0; r < 4; ++r) {
      int row = rb * 16 + quad * 4 + r;
      int rsw = (row >> 1) & 3;
      float sv0 = sA0[r] + sB0[r];
      float pv0 = valid0 ? exp2f(fmaf(sv0, LOG2E10, -mlg[r])) : 0.f;
      int seg0 = 0 * 2 + (ln >> 3);
      Pl[par][row * 32 + (seg0 ^ rsw) * 8 + (ln & 7)] = f2bf(pv0);
      float sv1 = sA1[r] + sB1[r];
      float pv1 = valid1 ? exp2f(fmaf(sv1, LOG2E10, -mlg[r])) : 0.f;
      int seg1 = 1 * 2 + (ln >> 3);
      Pl[par][row * 32 + (seg1 ^ rsw) * 8 + (ln & 7)] = f2bf(pv1);
      psum[r] += pv0 + pv1;
    }
    // counted-vmcnt barrier: steady state keeps R[ch+1]+B[ch+3] in flight.
    if (ch < c1 - 4) {
      asm volatile("s_waitcnt vmcnt(8) lgkmcnt(0)\n\ts_barrier" ::: "memory");
    } else {
      asm volatile("s_waitcnt vmcnt(0) lgkmcnt(0)\n\ts_barrier" ::: "memory");
    }
    // issue R first (older -> drained at next barrier), then B (3 ahead).
    if (ch + 1 < c1) stageR(ch + 1, par ^ 1);
    if (ch + 3 < c1) stageB(ch + 3, b3);   // (ch+3)%3 == ch%3: slot just freed by S(ch)
    // ---- Z(ch): rows zrh*64..+64, cols g*144..+144 ----
    bf16x8 pf[4];
    #pragma unroll
    for (int j = 0; j < 4; ++j)
      pf[j] = *(const bf16x8*)&Pl[par][(zrh * 64 + j * 16 + ln) * 32 + psw * 8];
    #pragma unroll
    for (int t = 0; t < 9; ++t) {
      int col = g * 144 + t * 16 + ln;
      int swz = quad ^ ((col >> 1) & 3);
      bf16x8 rf = *(const bf16x8*)&Rl[par][col * 32 + swz * 8];
      #pragma unroll
      for (int j = 0; j < 4; ++j)
        acc[j][t] = __builtin_amdgcn_mfma_f32_16x16x32_bf16(pf[j], rf, acc[j][t], 0, 0, 0);
    }
    b3 = b3 == 2 ? 0 : b3 + 1;
  }

  // reduce psum over the 16 lanes of each quad (sums both col halves)
  #pragma unroll
  for (int m = 1; m <= 8; m <<= 1)
    #pragma unroll
    for (int r = 0; r < 4; ++r) psum[r] += __shfl_xor(psum[r], m);
  int sb2 = spl * 2 + b;                 // 0..7
  if (ln == 0) {
    #pragma unroll
    for (int r = 0; r < 4; ++r) {
      int row = p0 + rb * 16 + quad * 4 + r;
      Ol[(size_t)sb2 * NPIX + row] = psum[r];
    }
  }
  #pragma unroll
  for (int j = 0; j < 4; ++j)
    #pragma unroll
    for (int t = 0; t < 9; ++t) {
      int colg = g * 144 + t * 16 + ln;
      #pragma unroll
      for (int r = 0; r < 4; ++r) {
        int row = p0 + zrh * 64 + j * 16 + quad * 4 + r;
        Og[((size_t)sb2 * NPIX + row) * 576 + colg] = acc[j][t][r];
      }
    }
}

// ---------------- K9: inv = 1 / sum of partial row-sums ----------------
template <int IS128>
__global__ void k_inv(const float* __restrict__ Ol, float* __restrict__ inv, int n) {
  int idx = blockIdx.x * 256 + threadIdx.x;
  if (idx >= n) return;                      // n = 2*NPIX
  int b = idx / NPIX; int p = idx % NPIX;
  float s = 0.f;
  if (IS128) {
    #pragma unroll
    for (int spl = 0; spl < 4; ++spl)
      s += Ol[(size_t)(spl * 2 + b) * NPIX + p];
  } else {
    #pragma unroll
    for (int spl = 0; spl < 2; ++spl)
      #pragma unroll
      for (int cbh = 0; cbh < 2; ++cbh)
        s += Ol[(size_t)(((spl * 2 + b) * 2) + cbh) * NPIX + p];
  }
  inv[idx] = 1.f / s;
}

// ---------------- K10: LDS-staged 9-tap gather, 512 threads ----------------
template <int NSL>
__global__ __launch_bounds__(512) void k_final(const float* __restrict__ Og,
                                               const float* __restrict__ inv,
                                               const float* __restrict__ input,
                                               float* __restrict__ out) {
  __shared__ float Srow[34][577];            // 78,472 B
  int blk = blockIdx.x;
  int xh = blk & 1; int y = (blk >> 1) & 63; int b = blk >> 7;
  int tid = threadIdx.x;
  const size_t S1 = (size_t)2 * NPIX * 576;  // plane stride between spl slices
  int x32 = tid & 31, c0 = (tid >> 5) * 4;   // 16 groups x 4 channels
  int qx0 = xh * 32 - 1;
  float acc[4];
  #pragma unroll
  for (int i = 0; i < 4; ++i) acc[i] = 0.f;

  for (int j = 0; j < 3; ++j) {
    int qy = y + 1 - j;
    if (qy < 0 || qy >= 64) continue;        // uniform across block
    for (int u = tid; u < 34 * 144; u += 512) {
      int k = u / 144; int f4 = u - k * 144;
      int qx = qx0 + k;
      float vx = 0.f, vy = 0.f, vz = 0.f, vw = 0.f;
      if (qx >= 0 && qx < 64) {
        int p = qy * 64 + qx;
        size_t e = ((size_t)b * NPIX + p) * 576 + f4 * 4;
        float iv = inv[b * NPIX + p];
        #pragma unroll
        for (int s = 0; s < NSL; ++s) {
          const float4 t4 = *(const float4*)(Og + e + (size_t)s * S1);
          vx += t4.x; vy += t4.y; vz += t4.z; vw += t4.w;
        }
        vx *= iv; vy *= iv; vz *= iv; vw *= iv;
      }
      float* d = &Srow[k][f4 * 4];
      d[0] = vx; d[1] = vy; d[2] = vz; d[3] = vw;
    }
    __syncthreads();
    #pragma unroll
    for (int i2 = 0; i2 < 3; ++i2) {
      int k = x32 + 2 - i2;
      #pragma unroll
      for (int cc = 0; cc < 4; ++cc)
        acc[cc] += Srow[k][(c0 + cc) * 9 + j * 3 + i2];
    }
    __syncthreads();
  }

  int x = xh * 32 + x32;
  #pragma unroll
  for (int cc = 0; cc < 4; ++cc) {
    int c = c0 + cc;
    int o = ((b * 64 + c) * 64 + y) * 64 + x;
    out[o] = 0.25f * acc[cc] + input[o];
  }
}

extern "C" void kernel_launch(void* const* d_in, const int* in_sizes, int n_in,
                              void* d_out, int out_size, void* d_ws, size_t ws_size,
                              hipStream_t stream) {
  (void)in_sizes; (void)n_in; (void)out_size;
  const float* input = (const float*)d_in[0];
  const float* inref = (const float*)d_in[1];
  const float* Wb = (const float*)d_in[2];
  const float* bb = (const float*)d_in[3];
  const float* Wm = (const float*)d_in[4];
  const float* bm = (const float*)d_in[5];
  const float* Wa = (const float*)d_in[6];
  const float* ba = (const float*)d_in[7];
  const float* ap = (const float*)d_in[8];
  float* out = (float*)d_out;

  char* ws = (char*)d_ws;
  size_t off = 0;
  auto alloc = [&](size_t bytes) -> char* {
    char* p = ws + off; off = (off + bytes + 255) & ~(size_t)255; return p;
  };
  // persistent region
  ushort_t* Am   = (ushort_t*)alloc((size_t)2 * NPIX * 288 * 2);        // 4.7 MB
  ushort_t* Bs   = (ushort_t*)alloc((size_t)2 * NCHT * BCHUNK_E * 2);   // 15.4 MB
  ushort_t* Rs   = (ushort_t*)alloc((size_t)2 * NCHT * RCHUNK_E * 2);   // 30.7 MB
  float*    Ol   = (float*)alloc((size_t)16 * NPIX * 4);
  float*    inv  = (float*)alloc((size_t)2 * NPIX * 4);
  float*    Mlog = (float*)alloc((size_t)2 * NPIX * 4);
  float*    ssqA = (float*)alloc((size_t)2 * NPIX * 4);
  // big region: Og aliases the early prep buffers.
  size_t og64  = (size_t)4 * NPIX * 576 * 4;   // 37.7 MB (2 slices per b)
  size_t og128 = og64 * 2;                     // 75.5 MB (4 slices per b)
  bool use128 = (off + og128 + 512) <= ws_size;
  char* big = alloc(use128 ? og128 : og64);
  float* Og = (float*)big;
  size_t eoff = 0;
  auto ealloc = [&](size_t bytes) -> char* {
    char* p = big + eoff; eoff = (eoff + bytes + 255) & ~(size_t)255; return p;
  };
  float* mref = (float*)ealloc((size_t)2 * 32 * L_TOT * 4);
  float* aref = (float*)ealloc((size_t)2 * 64 * L_TOT * 4);
  float* mbb  = (float*)ealloc((size_t)2 * 32 * NPIX * 4);
  float* ssq  = (float*)ealloc((size_t)2 * L_TOT * 4);
  float* invn = (float*)ealloc((size_t)2 * L_TOT * 4);

  k_convref<<<212, 256, 0, stream>>>(inref, Wm, bm, Wa, ba, ap, mref, aref);
  int n3 = 2 * 32 * NPIX;
  k_mb<<<(n3 + 255) / 256, 256, 0, stream>>>(input, Wb, bb, ap, mbb, n3);
  int ns = 2 * L_TOT + 2 * NPIX;
  k_stage1<<<(ns + 255) / 256, 256, 0, stream>>>(mref, mbb, ssq, ssqA, ns);
  k_stage2<<<(ns + 255) / 256, 256, 0, stream>>>(ssq, ssqA, invn, Mlog, ns);
  int np = N_BS + N_AIM + N_RS;
  k_pack<<<(np + 255) / 256, 256, 0, stream>>>(mref, invn, mbb, aref, Bs, Am, Rs, np);

  if (use128) {
    k_attn128<<<256, 512, 0, stream>>>(Am, Bs, Rs, Mlog, Og, Ol);
    k_inv<1><<<(2 * NPIX + 255) / 256, 256, 0, stream>>>(Ol, inv, 2 * NPIX);
    k_final<4><<<256, 512, 0, stream>>>(Og, inv, input, out);
  } else {
    k_attn64<<<256, 512, 0, stream>>>(Am, Bs, Rs, Mlog, Og, Ol);
    k_inv<0><<<(2 * NPIX + 255) / 256, 256, 0, stream>>>(Ol, inv, 2 * NPIX);
    k_final<2><<<256, 512, 0, stream>>>(Og, inv, input, out);
  }
}

// Round 12
// 434.001 us; speedup vs baseline: 1.0102x; 1.0102x over previous
//
#include <hip/hip_runtime.h>
#include <stdint.h>

// PyramidAttention gfx950 — round 25: revert to R23 (435us, session best).
// R24's counted-vmcnt barrier was neutral (+3.6us): the per-chunk stall is
// dep-chain latency at 2 waves/SIMD, not DMA drain. 2 waves/SIMD is pinned by
// the register ledger (acc 144 AGPR + af 36 + misc ~= 245/wave; >2 waves
// needs <=128). Five restructuring attempts (R14/15/16/19/24) all confirm.
// Chain (~203us) rejected staging (R21) and extra passes (R22): cache-
// resident + TLP-saturated. This file is byte-identical to R23.

typedef __attribute__((ext_vector_type(8))) short bf16x8;
typedef __attribute__((ext_vector_type(4))) float f32x4;
typedef unsigned short ushort_t;

#define L_TOT  13326
#define NCHT   417
#define NPIX   4096
#define BCHUNK_E 9216  // 32 cols * 288 k
#define RCHUNK_E 18432 // 576 cols * 32 l
#define LOG2E10 14.4269504f   // 10*log2(e)
#define CT 256         // k_convref l-tile

__device__ __forceinline__ float cubw(float d) {
  d = fabsf(d);
  if (d <= 1.f) return (1.25f * d - 2.25f) * d * d + 1.f;          // A=-0.75
  if (d < 2.f)  return ((-0.75f * d + 3.75f) * d - 6.f) * d + 3.f;
  return 0.f;
}

__device__ __forceinline__ void decode_l(int l, int& S, int& off) {
  if (l < 4096)       { S = 64; off = 0; }
  else if (l < 7345)  { S = 57; off = 4096; }
  else if (l < 9946)  { S = 51; off = 7345; }
  else if (l < 11882) { S = 44; off = 9946; }
  else                { S = 38; off = 11882; }
}

__device__ __forceinline__ ushort_t f2bf(float f) {
  union { float f; uint32_t u; } v; v.f = f;
  uint32_t r = (v.u + 0x7fffu + ((v.u >> 16) & 1u)) >> 16;  // RNE
  return (ushort_t)r;
}

__device__ __forceinline__ float preluf(float x, float a) { return x >= 0.f ? x : a * x; }

__device__ __forceinline__ void gll16(const ushort_t* g, ushort_t* l) {
  __builtin_amdgcn_global_load_lds(
      (const __attribute__((address_space(1))) unsigned int*)g,
      (__attribute__((address_space(3))) unsigned int*)l, 16, 0, 0);
}

// ---------------- K2: bicubic + conv1x1 + prelu fused ----------------
__global__ void k_convref(const float* __restrict__ inref,
                          const float* __restrict__ Wm, const float* __restrict__ bm,
                          const float* __restrict__ Wa, const float* __restrict__ ba,
                          const float* __restrict__ ap,
                          float* __restrict__ mref, float* __restrict__ aref) {
  __shared__ float T[64][CT];
  __shared__ float Wy[CT][5], Wx[CT][5];
  __shared__ int   IY[CT], IX[CT];
  int blk = blockIdx.x;
  int oh = blk & 1; int lt = (blk >> 1) % 53; int b = blk / 106;
  int l0 = lt * CT;
  int tid = threadIdx.x;
  float a = ap[0];
  {
    int gl = l0 + tid;
    if (gl < L_TOT) {
      int S, off; decode_l(gl, S, off);
      int li = gl - off; int ly = li / S, lx = li % S;
      if (S == 64) {
        IY[tid] = -1; IX[tid] = ly * 64 + lx;
      } else {
        float sc = (float)(63.0 / (double)(S - 1));
        float sy = (float)ly * sc, sx = (float)lx * sc;
        int iy = (int)floorf(sy), ix = (int)floorf(sx);
        float fy = sy - (float)iy, fx = sx - (float)ix;
        IY[tid] = iy; IX[tid] = ix;
        Wy[tid][0] = cubw(fy + 1.f); Wy[tid][1] = cubw(fy);
        Wy[tid][2] = cubw(1.f - fy); Wy[tid][3] = cubw(2.f - fy);
        Wx[tid][0] = cubw(fx + 1.f); Wx[tid][1] = cubw(fx);
        Wx[tid][2] = cubw(1.f - fx); Wx[tid][3] = cubw(2.f - fx);
      }
    }
  }
  __syncthreads();
  for (int i = tid; i < 64 * CT; i += 256) {
    int c = i >> 8; int l2 = i & 255;
    int gl = l0 + l2;
    float val = 0.f;
    if (gl < L_TOT) {
      const float* img = inref + (size_t)(b * 64 + c) * 4096;
      int iy = IY[l2];
      if (iy == -1) {
        val = img[IX[l2]];
      } else {
        int ix = IX[l2];
        #pragma unroll
        for (int t = 0; t < 4; ++t) {
          int ty = iy - 1 + t; ty = ty < 0 ? 0 : (ty > 63 ? 63 : ty);
          float rv = 0.f;
          #pragma unroll
          for (int u = 0; u < 4; ++u) {
            int tx = ix - 1 + u; tx = tx < 0 ? 0 : (tx > 63 ? 63 : tx);
            rv += Wx[l2][u] * img[ty * 64 + tx];
          }
          val += Wy[l2][t] * rv;
        }
      }
    }
    T[c][l2] = val;
  }
  __syncthreads();
  int gl = l0 + tid;
  if (gl >= L_TOT) return;
  for (int oc = oh * 48; oc < oh * 48 + 48; ++oc) {
    const float* Wrow; float s;
    if (oc < 32) { Wrow = Wm + oc * 64; s = bm[oc]; }
    else         { Wrow = Wa + (oc - 32) * 64; s = ba[oc - 32]; }
    #pragma unroll 8
    for (int c = 0; c < 64; ++c) s += Wrow[c] * T[c][tid];
    s = preluf(s, a);
    if (oc < 32) mref[(size_t)(b * 32 + oc) * L_TOT + gl] = s;
    else         aref[(size_t)(b * 64 + oc - 32) * L_TOT + gl] = s;
  }
}

// ---------------- K3: match_base = prelu(Wb@input+bb) ----------------
__global__ void k_mb(const float* __restrict__ input, const float* __restrict__ Wb,
                     const float* __restrict__ bb, const float* __restrict__ ap,
                     float* __restrict__ mbb, int n) {
  int idx = blockIdx.x * 256 + threadIdx.x;
  if (idx >= n) return;                      // n = 2*32*NPIX
  int p = idx % NPIX; int cm = (idx / NPIX) % 32; int b = idx / (32 * NPIX);
  float a = ap[0];
  float acc = bb[cm];
  for (int c = 0; c < 64; ++c) acc += Wb[cm * 64 + c] * input[(size_t)(b * 64 + c) * NPIX + p];
  mbb[(size_t)(b * 32 + cm) * NPIX + p] = preluf(acc, a);
}

// ---------------- K4s1: ssq U ssqA ----------------
__global__ void k_stage1(const float* __restrict__ mref, const float* __restrict__ mbb,
                         float* __restrict__ ssq, float* __restrict__ ssqA, int n) {
  int idx = blockIdx.x * 256 + threadIdx.x;
  if (idx >= n) return;                      // n = 2*L_TOT + 2*NPIX
  if (idx < 2 * L_TOT) {
    int l = idx % L_TOT; int b = idx / L_TOT;
    float s = 0.f;
    for (int c = 0; c < 32; ++c) { float v = mref[(size_t)(b * 32 + c) * L_TOT + l]; s += v * v; }
    ssq[idx] = s;
  } else {
    int j = idx - 2 * L_TOT;
    int p = j % NPIX; int b = j / NPIX;
    float s = 0.f;
    for (int c = 0; c < 32; ++c) { float v = mbb[(size_t)(b * 32 + c) * NPIX + p]; s += v * v; }
    ssqA[j] = s;
  }
}

// ---------------- K4s2: invn U Mlog ----------------
__global__ void k_stage2(const float* __restrict__ ssq, const float* __restrict__ ssqA,
                         float* __restrict__ invn, float* __restrict__ Mlog, int n) {
  int idx = blockIdx.x * 256 + threadIdx.x;
  if (idx >= n) return;                      // n = 2*L_TOT + 2*NPIX
  if (idx < 2 * L_TOT) {
    int l = idx % L_TOT; int b = idx / L_TOT;
    int S, off; decode_l(l, S, off);
    int li = l - off; int ly = li / S, lx = li % S;
    float acc = 0.f;
    for (int dy = -1; dy <= 1; ++dy) {
      int ny = ly + dy; if (ny < 0 || ny >= S) continue;
      for (int dx = -1; dx <= 1; ++dx) {
        int nx = lx + dx; if (nx < 0 || nx >= S) continue;
        acc += ssq[(size_t)b * L_TOT + off + ny * S + nx];
      }
    }
    float nrm = sqrtf(acc); nrm = fmaxf(nrm, 1e-4f);
    invn[idx] = 1.f / nrm;
  } else {
    int j = idx - 2 * L_TOT;
    int p = j % NPIX; int b = j / NPIX;
    int y = p / 64, x = p % 64;
    float acc = 0.f;
    for (int dy = -1; dy <= 1; ++dy) {
      int ny = y + dy; if (ny < 0 || ny >= 64) continue;
      for (int dx = -1; dx <= 1; ++dx) {
        int nx = x + dx; if (nx < 0 || nx >= 64) continue;
        acc += ssqA[(size_t)b * NPIX + ny * 64 + nx];
      }
    }
    float qn = sqrtf(acc);
    float m = fmaxf(0.7f * qn, qn - 7.f);
    Mlog[j] = LOG2E10 * m;
  }
}

// ---------------- K5/6/7 merged: Bs U Am U Rs packing, vec8 ----------------
#define N_BS (2 * NCHT * 1152)
#define N_AIM (2 * NPIX * 36)
#define N_RS (2 * NCHT * 576 * 4)
__global__ void k_pack(const float* __restrict__ mref, const float* __restrict__ invn,
                       const float* __restrict__ mbb, const float* __restrict__ aref,
                       ushort_t* __restrict__ Bs, ushort_t* __restrict__ Am,
                       ushort_t* __restrict__ Rs, int n) {
  int idx = blockIdx.x * 256 + threadIdx.x;
  if (idx >= n) return;
  ushort_t v[8];
  if (idx < N_BS) {
    int segp = idx % 36; int col = (idx / 36) % 32;
    int ch = (idx / 1152) % NCHT; int b = idx / (1152 * NCHT);
    int segl = (segp & ~3) | ((segp & 3) ^ ((col >> 1) & 3));
    int l = ch * 32 + col;
    if (l < L_TOT) {
      int S, off; decode_l(l, S, off);
      int li = l - off; int ly = li / S, lx = li % S;
      float iv = invn[(size_t)b * L_TOT + l];
      #pragma unroll
      for (int e = 0; e < 8; ++e) {
        int k = segl * 8 + e;
        int c = k / 9; int r = k % 9; int dy = r / 3 - 1, dx = r % 3 - 1;
        int ny = ly + dy, nx = lx + dx;
        float val = 0.f;
        if (ny >= 0 && ny < S && nx >= 0 && nx < S)
          val = mref[(size_t)(b * 32 + c) * L_TOT + off + ny * S + nx] * iv;
        v[e] = f2bf(val);
      }
    } else {
      #pragma unroll
      for (int e = 0; e < 8; ++e) v[e] = 0;
    }
    *(uint4*)(Bs + ((size_t)(b * NCHT + ch) * BCHUNK_E + col * 288 + segp * 8)) = *(const uint4*)v;
  } else if (idx < N_BS + N_AIM) {
    int j = idx - N_BS;
    int k8 = j % 36; int p = (j / 36) % NPIX; int b = j / (36 * NPIX);
    int y = p / 64, x = p % 64;
    #pragma unroll
    for (int e = 0; e < 8; ++e) {
      int k = k8 * 8 + e;
      int c = k / 9; int r = k % 9; int dy = r / 3 - 1, dx = r % 3 - 1;
      int ny = y + dy, nx = x + dx;
      float val = 0.f;
      if (ny >= 0 && ny < 64 && nx >= 0 && nx < 64)
        val = mbb[(size_t)(b * 32 + c) * NPIX + ny * 64 + nx];
      v[e] = f2bf(val);
    }
    *(uint4*)(Am + ((size_t)(b * NPIX + p) * 288 + k8 * 8)) = *(const uint4*)v;
  } else {
    int j = idx - N_BS - N_AIM;
    int phys = j & 3; int q = j >> 2;
    int col = q % 576; q /= 576;
    int ch = q % NCHT; int b = q / NCHT;
    int c = col / 9; int r = col % 9; int dy = r / 3 - 1, dx = r % 3 - 1;
    int seg = phys ^ ((col >> 1) & 3);
    int lbase = ch * 32 + seg * 8;
    #pragma unroll
    for (int e = 0; e < 8; ++e) {
      int l = lbase + e;
      float val = 0.f;
      if (l < L_TOT) {
        int S, off; decode_l(l, S, off);
        int li = l - off; int ly = li / S, lx = li % S;
        int ny = ly + dy, nx = lx + dx;
        if (ny >= 0 && ny < S && nx >= 0 && nx < S)
          val = aref[(size_t)(b * 64 + c) * L_TOT + off + ny * S + nx];
      }
      v[e] = f2bf(val);
    }
    *(uint4*)(Rs + ((size_t)(b * NCHT + ch) * RCHUNK_E + col * 32 + phys * 8)) = *(const uint4*)v;
  }
}

// ---------------- K8a: M=64 flash attention (R13 proven fallback) ----------------
__global__ __launch_bounds__(512, 2) void k_attn64(const ushort_t* __restrict__ Am,
                                                   const ushort_t* __restrict__ Bs,
                                                   const ushort_t* __restrict__ Rs,
                                                   const float* __restrict__ Mlog,
                                                   float* __restrict__ Og,
                                                   float* __restrict__ Ol) {
  __shared__ ushort_t Rl[3][RCHUNK_E];
  __shared__ ushort_t Bl[2][BCHUNK_E];
  __shared__ ushort_t Pl[2][2048];
  int tid = threadIdx.x;
  int xcd = blockIdx.x & 7; int slot = blockIdx.x >> 3;
  int group = xcd >> 1;
  int spl = group & 1; int b = group >> 1;
  int tile = slot * 2 + (xcd & 1);
  int p0 = tile * 64;
  int wave = tid >> 6, lane = tid & 63, quad = lane >> 4, ln = lane & 15;
  int rbS = wave & 3, cbh = wave >> 2;
  int g = wave & 3, zrh = wave >> 2;
  int c0 = spl ? 209 : 0, c1 = spl ? NCHT : 209;

  bf16x8 af[9];
  {
    const ushort_t* arow = Am + (size_t)(b * NPIX + p0 + rbS * 16 + ln) * 288;
    #pragma unroll
    for (int kk = 0; kk < 9; ++kk) af[kk] = *(const bf16x8*)(arow + kk * 32 + quad * 8);
  }
  float mlg[4];
  #pragma unroll
  for (int r = 0; r < 4; ++r)
    mlg[r] = Mlog[(size_t)b * NPIX + p0 + rbS * 16 + quad * 4 + r];

  f32x4 acc[2][9];
  #pragma unroll
  for (int h = 0; h < 2; ++h)
    #pragma unroll
    for (int t = 0; t < 9; ++t) { acc[h][t][0] = acc[h][t][1] = acc[h][t][2] = acc[h][t][3] = 0.f; }
  float psum[4] = {0.f, 0.f, 0.f, 0.f};

  const ushort_t* RsB = Rs + (size_t)b * NCHT * RCHUNK_E + lane * 8;
  const ushort_t* BsB = Bs + (size_t)b * NCHT * BCHUNK_E + lane * 8;

  {
    const ushort_t* sB0 = BsB + (size_t)c0 * BCHUNK_E;
    ushort_t* dB0 = Bl[c0 & 1];
    #pragma unroll
    for (int u = wave; u < 18; u += 8) gll16(sB0 + u * 512, dB0 + u * 512);
    const ushort_t* sB1 = BsB + (size_t)(c0 + 1) * BCHUNK_E;
    ushort_t* dB1 = Bl[(c0 + 1) & 1];
    #pragma unroll
    for (int u = wave; u < 18; u += 8) gll16(sB1 + u * 512, dB1 + u * 512);
    const ushort_t* sR = RsB + (size_t)c0 * RCHUNK_E;
    ushort_t* dR = Rl[c0 % 3];
    #pragma unroll
    for (int u = wave; u < 36; u += 8) gll16(sR + u * 512, dR + u * 512);
  }
  __syncthreads();

  int col32 = cbh * 16 + ln;
  int bswz = (col32 >> 1) & 3;
  int rpar = c0 % 3;
  for (int ch = c0; ch < c1; ++ch) {
    int par = ch & 1;
    int rnext = rpar == 2 ? 0 : rpar + 1;
    f32x4 sa, sb;
    sa[0] = sa[1] = sa[2] = sa[3] = 0.f;
    sb[0] = sb[1] = sb[2] = sb[3] = 0.f;
    #pragma unroll
    for (int kk = 0; kk < 9; ++kk) {
      int segp = kk * 4 + (quad ^ bswz);
      bf16x8 bf = *(const bf16x8*)&Bl[par][col32 * 288 + segp * 8];
      if (kk == 4 || kk == 5 || kk == 6 || kk == 7)
        sb = __builtin_amdgcn_mfma_f32_16x16x32_bf16(af[kk], bf, sb, 0, 0, 0);
      else
        sa = __builtin_amdgcn_mfma_f32_16x16x32_bf16(af[kk], bf, sa, 0, 0, 0);
    }
    int colw = ch * 32 + col32;
    bool valid = colw < L_TOT;
    #pragma unroll
    for (int r = 0; r < 4; ++r) {
      float sv = sa[r] + sb[r];
      float pv = valid ? exp2f(fmaf(sv, LOG2E10, -mlg[r])) : 0.f;
      int row = rbS * 16 + quad * 4 + r;
      int seg = cbh * 2 + (ln >> 3);
      int swz = seg ^ ((row >> 1) & 3);
      Pl[par][row * 32 + swz * 8 + (ln & 7)] = f2bf(pv);
      psum[r] += pv;
    }
    __syncthreads();
    if (ch + 2 < c1) {
      const ushort_t* sB = BsB + (size_t)(ch + 2) * BCHUNK_E;
      ushort_t* dB = Bl[par];
      #pragma unroll
      for (int u = wave; u < 18; u += 8) gll16(sB + u * 512, dB + u * 512);
    }
    if (ch + 1 < c1) {
      const ushort_t* sR = RsB + (size_t)(ch + 1) * RCHUNK_E;
      ushort_t* dR = Rl[rnext];
      #pragma unroll
      for (int u = wave; u < 36; u += 8) gll16(sR + u * 512, dR + u * 512);
    }
    bf16x8 pf0, pf1;
    {
      int sw = quad ^ ((ln >> 1) & 3);
      pf0 = *(const bf16x8*)&Pl[par][(zrh * 32 + ln) * 32 + sw * 8];
      pf1 = *(const bf16x8*)&Pl[par][(zrh * 32 + 16 + ln) * 32 + sw * 8];
    }
    #pragma unroll
    for (int t = 0; t < 9; ++t) {
      int col = g * 144 + t * 16 + ln;
      int swz = quad ^ ((col >> 1) & 3);
      bf16x8 rf = *(const bf16x8*)&Rl[rpar][col * 32 + swz * 8];
      acc[0][t] = __builtin_amdgcn_mfma_f32_16x16x32_bf16(pf0, rf, acc[0][t], 0, 0, 0);
      acc[1][t] = __builtin_amdgcn_mfma_f32_16x16x32_bf16(pf1, rf, acc[1][t], 0, 0, 0);
    }
    rpar = rnext;
  }

  #pragma unroll
  for (int m = 1; m <= 8; m <<= 1)
    #pragma unroll
    for (int r = 0; r < 4; ++r) psum[r] += __shfl_xor(psum[r], m);
  int sb2 = spl * 2 + b;
  if (ln == 0) {
    #pragma unroll
    for (int r = 0; r < 4; ++r) {
      int row = p0 + rbS * 16 + quad * 4 + r;
      Ol[(size_t)(sb2 * 2 + cbh) * NPIX + row] = psum[r];
    }
  }
  #pragma unroll
  for (int h = 0; h < 2; ++h)
    #pragma unroll
    for (int t = 0; t < 9; ++t) {
      int colg = g * 144 + t * 16 + ln;
      #pragma unroll
      for (int r = 0; r < 4; ++r) {
        int row = p0 + zrh * 32 + h * 16 + quad * 4 + r;
        Og[((size_t)sb2 * NPIX + row) * 576 + colg] = acc[h][t][r];
      }
    }
}

// ---------------- K8b: M=128 flash attention, register-fitted (R18 exact, 232us) ----------------
__global__ __launch_bounds__(512, 2) void k_attn128(const ushort_t* __restrict__ Am,
                                                    const ushort_t* __restrict__ Bs,
                                                    const ushort_t* __restrict__ Rs,
                                                    const float* __restrict__ Mlog,
                                                    float* __restrict__ Og,
                                                    float* __restrict__ Ol) {
  __shared__ ushort_t Rl[2][RCHUNK_E];   // 73728 B
  __shared__ ushort_t Bl[2][BCHUNK_E];   // 36864 B
  __shared__ ushort_t Pl[2][4096];       // 16384 B: dbuf P tile 128x32 (swizzled)
  int tid = threadIdx.x;
  int xcd = blockIdx.x & 7; int slot = blockIdx.x >> 3;
  int spl = xcd >> 1; int b = xcd & 1;
  int p0 = slot * 128;
  int wave = tid >> 6, lane = tid & 63, quad = lane >> 4, ln = lane & 15;
  int rb = wave;                          // S role: one 16-row block
  int g = wave & 3, zrh = wave >> 2;      // Z role
  int c0 = (spl * NCHT) >> 2;             // 0,104,208,312 (even)
  int c1 = ((spl + 1) * NCHT) >> 2;       // 104,208,312,417

  bf16x8 af[9];
  {
    const ushort_t* arow = Am + (size_t)(b * NPIX + p0 + rb * 16 + ln) * 288;
    #pragma unroll
    for (int kk = 0; kk < 9; ++kk) af[kk] = *(const bf16x8*)(arow + kk * 32 + quad * 8);
  }
  float mlg[4], psum[4];
  #pragma unroll
  for (int r = 0; r < 4; ++r) {
    mlg[r] = Mlog[(size_t)b * NPIX + p0 + rb * 16 + quad * 4 + r];
    psum[r] = 0.f;
  }
  f32x4 acc[4][9];
  #pragma unroll
  for (int j = 0; j < 4; ++j)
    #pragma unroll
    for (int t = 0; t < 9; ++t) { acc[j][t][0] = acc[j][t][1] = acc[j][t][2] = acc[j][t][3] = 0.f; }

  const ushort_t* RsB = Rs + (size_t)b * NCHT * RCHUNK_E + lane * 8;
  const ushort_t* BsB = Bs + (size_t)b * NCHT * BCHUNK_E + lane * 8;

  auto stageB = [&](int chunk, int sl) {
    const ushort_t* s = BsB + (size_t)chunk * BCHUNK_E;
    ushort_t* d = Bl[sl];
    #pragma unroll
    for (int u = wave; u < 18; u += 8) gll16(s + u * 512, d + u * 512);
  };
  auto stageR = [&](int chunk, int sl) {
    const ushort_t* s = RsB + (size_t)chunk * RCHUNK_E;
    ushort_t* d = Rl[sl];
    #pragma unroll
    for (int u = wave; u < 36; u += 8) gll16(s + u * 512, d + u * 512);
  };

  int bswz = (ln >> 1) & 3;               // ((cb*16+ln)>>1)&3 is cb-invariant
  int psw = quad ^ ((ln >> 1) & 3);

  stageB(c0, 0);
  stageB(c0 + 1, 1);
  stageR(c0, 0);
  __syncthreads();

  for (int ch = c0; ch < c1; ++ch) {
    int par = ch & 1;
    // ---- S(ch): rows rb*16..+16, cols 0..31 (both halves) ----
    f32x4 sA0, sB0, sA1, sB1;
    sA0[0]=sA0[1]=sA0[2]=sA0[3]=0.f; sB0[0]=sB0[1]=sB0[2]=sB0[3]=0.f;
    sA1[0]=sA1[1]=sA1[2]=sA1[3]=0.f; sB1[0]=sB1[1]=sB1[2]=sB1[3]=0.f;
    #pragma unroll
    for (int kk = 0; kk < 9; ++kk) {
      int segp = kk * 4 + (quad ^ bswz);
      bf16x8 bf0 = *(const bf16x8*)&Bl[par][(ln) * 288 + segp * 8];
      bf16x8 bf1 = *(const bf16x8*)&Bl[par][(16 + ln) * 288 + segp * 8];
      if (kk >= 4 && kk <= 7) {
        sB0 = __builtin_amdgcn_mfma_f32_16x16x32_bf16(af[kk], bf0, sB0, 0, 0, 0);
        sB1 = __builtin_amdgcn_mfma_f32_16x16x32_bf16(af[kk], bf1, sB1, 0, 0, 0);
      } else {
        sA0 = __builtin_amdgcn_mfma_f32_16x16x32_bf16(af[kk], bf0, sA0, 0, 0, 0);
        sA1 = __builtin_amdgcn_mfma_f32_16x16x32_bf16(af[kk], bf1, sA1, 0, 0, 0);
      }
    }
    bool valid0 = ch * 32 + ln < L_TOT;
    bool valid1 = ch * 32 + 16 + ln < L_TOT;
    #pragma unroll
    for (int r = 0; r < 4; ++r) {
      int row = rb * 16 + quad * 4 + r;
      int rsw = (row >> 1) & 3;
      float sv0 = sA0[r] + sB0[r];
      float pv0 = valid0 ? exp2f(fmaf(sv0, LOG2E10, -mlg[r])) : 0.f;
      int seg0 = 0 * 2 + (ln >> 3);
      Pl[par][row * 32 + (seg0 ^ rsw) * 8 + (ln & 7)] = f2bf(pv0);
      float sv1 = sA1[r] + sB1[r];
      float pv1 = valid1 ? exp2f(fmaf(sv1, LOG2E10, -mlg[r])) : 0.f;
      int seg1 = 1 * 2 + (ln >> 3);
      Pl[par][row * 32 + (seg1 ^ rsw) * 8 + (ln & 7)] = f2bf(pv1);
      psum[r] += pv0 + pv1;
    }
    __syncthreads();
    if (ch + 2 < c1) stageB(ch + 2, par);
    if (ch + 1 < c1) stageR(ch + 1, par ^ 1);
    // ---- Z(ch): rows zrh*64..+64, cols g*144..+144 ----
    bf16x8 pf[4];
    #pragma unroll
    for (int j = 0; j < 4; ++j)
      pf[j] = *(const bf16x8*)&Pl[par][(zrh * 64 + j * 16 + ln) * 32 + psw * 8];
    #pragma unroll
    for (int t = 0; t < 9; ++t) {
      int col = g * 144 + t * 16 + ln;
      int swz = quad ^ ((col >> 1) & 3);
      bf16x8 rf = *(const bf16x8*)&Rl[par][col * 32 + swz * 8];
      #pragma unroll
      for (int j = 0; j < 4; ++j)
        acc[j][t] = __builtin_amdgcn_mfma_f32_16x16x32_bf16(pf[j], rf, acc[j][t], 0, 0, 0);
    }
  }

  // reduce psum over the 16 lanes of each quad (sums both col halves)
  #pragma unroll
  for (int m = 1; m <= 8; m <<= 1)
    #pragma unroll
    for (int r = 0; r < 4; ++r) psum[r] += __shfl_xor(psum[r], m);
  int sb2 = spl * 2 + b;                 // 0..7
  if (ln == 0) {
    #pragma unroll
    for (int r = 0; r < 4; ++r) {
      int row = p0 + rb * 16 + quad * 4 + r;
      Ol[(size_t)sb2 * NPIX + row] = psum[r];
    }
  }
  #pragma unroll
  for (int j = 0; j < 4; ++j)
    #pragma unroll
    for (int t = 0; t < 9; ++t) {
      int colg = g * 144 + t * 16 + ln;
      #pragma unroll
      for (int r = 0; r < 4; ++r) {
        int row = p0 + zrh * 64 + j * 16 + quad * 4 + r;
        Og[((size_t)sb2 * NPIX + row) * 576 + colg] = acc[j][t][r];
      }
    }
}

// ---------------- K9: inv = 1 / sum of partial row-sums ----------------
template <int IS128>
__global__ void k_inv(const float* __restrict__ Ol, float* __restrict__ inv, int n) {
  int idx = blockIdx.x * 256 + threadIdx.x;
  if (idx >= n) return;                      // n = 2*NPIX
  int b = idx / NPIX; int p = idx % NPIX;
  float s = 0.f;
  if (IS128) {
    #pragma unroll
    for (int spl = 0; spl < 4; ++spl)
      s += Ol[(size_t)(spl * 2 + b) * NPIX + p];
  } else {
    #pragma unroll
    for (int spl = 0; spl < 2; ++spl)
      #pragma unroll
      for (int cbh = 0; cbh < 2; ++cbh)
        s += Ol[(size_t)(((spl * 2 + b) * 2) + cbh) * NPIX + p];
  }
  inv[idx] = 1.f / s;
}

// ---------------- K10: LDS-staged 9-tap gather, 512 threads (2 waves/SIMD) ----------------
template <int NSL>
__global__ __launch_bounds__(512) void k_final(const float* __restrict__ Og,
                                               const float* __restrict__ inv,
                                               const float* __restrict__ input,
                                               float* __restrict__ out) {
  __shared__ float Srow[34][577];            // 78,472 B
  int blk = blockIdx.x;
  int xh = blk & 1; int y = (blk >> 1) & 63; int b = blk >> 7;
  int tid = threadIdx.x;
  const size_t S1 = (size_t)2 * NPIX * 576;  // plane stride between spl slices
  int x32 = tid & 31, c0 = (tid >> 5) * 4;   // 16 groups x 4 channels
  int qx0 = xh * 32 - 1;
  float acc[4];
  #pragma unroll
  for (int i = 0; i < 4; ++i) acc[i] = 0.f;

  for (int j = 0; j < 3; ++j) {
    int qy = y + 1 - j;
    if (qy < 0 || qy >= 64) continue;        // uniform across block
    for (int u = tid; u < 34 * 144; u += 512) {
      int k = u / 144; int f4 = u - k * 144;
      int qx = qx0 + k;
      float vx = 0.f, vy = 0.f, vz = 0.f, vw = 0.f;
      if (qx >= 0 && qx < 64) {
        int p = qy * 64 + qx;
        size_t e = ((size_t)b * NPIX + p) * 576 + f4 * 4;
        float iv = inv[b * NPIX + p];
        #pragma unroll
        for (int s = 0; s < NSL; ++s) {
          const float4 t4 = *(const float4*)(Og + e + (size_t)s * S1);
          vx += t4.x; vy += t4.y; vz += t4.z; vw += t4.w;
        }
        vx *= iv; vy *= iv; vz *= iv; vw *= iv;
      }
      float* d = &Srow[k][f4 * 4];
      d[0] = vx; d[1] = vy; d[2] = vz; d[3] = vw;
    }
    __syncthreads();
    #pragma unroll
    for (int i2 = 0; i2 < 3; ++i2) {
      int k = x32 + 2 - i2;
      #pragma unroll
      for (int cc = 0; cc < 4; ++cc)
        acc[cc] += Srow[k][(c0 + cc) * 9 + j * 3 + i2];
    }
    __syncthreads();
  }

  int x = xh * 32 + x32;
  #pragma unroll
  for (int cc = 0; cc < 4; ++cc) {
    int c = c0 + cc;
    int o = ((b * 64 + c) * 64 + y) * 64 + x;
    out[o] = 0.25f * acc[cc] + input[o];
  }
}

extern "C" void kernel_launch(void* const* d_in, const int* in_sizes, int n_in,
                              void* d_out, int out_size, void* d_ws, size_t ws_size,
                              hipStream_t stream) {
  (void)in_sizes; (void)n_in; (void)out_size;
  const float* input = (const float*)d_in[0];
  const float* inref = (const float*)d_in[1];
  const float* Wb = (const float*)d_in[2];
  const float* bb = (const float*)d_in[3];
  const float* Wm = (const float*)d_in[4];
  const float* bm = (const float*)d_in[5];
  const float* Wa = (const float*)d_in[6];
  const float* ba = (const float*)d_in[7];
  const float* ap = (const float*)d_in[8];
  float* out = (float*)d_out;

  char* ws = (char*)d_ws;
  size_t off = 0;
  auto alloc = [&](size_t bytes) -> char* {
    char* p = ws + off; off = (off + bytes + 255) & ~(size_t)255; return p;
  };
  // persistent region
  ushort_t* Am   = (ushort_t*)alloc((size_t)2 * NPIX * 288 * 2);        // 4.7 MB
  ushort_t* Bs   = (ushort_t*)alloc((size_t)2 * NCHT * BCHUNK_E * 2);   // 15.4 MB
  ushort_t* Rs   = (ushort_t*)alloc((size_t)2 * NCHT * RCHUNK_E * 2);   // 30.7 MB
  float*    Ol   = (float*)alloc((size_t)16 * NPIX * 4);
  float*    inv  = (float*)alloc((size_t)2 * NPIX * 4);
  float*    Mlog = (float*)alloc((size_t)2 * NPIX * 4);
  float*    ssqA = (float*)alloc((size_t)2 * NPIX * 4);
  // big region: Og aliases the early prep buffers.
  size_t og64  = (size_t)4 * NPIX * 576 * 4;   // 37.7 MB (2 slices per b)
  size_t og128 = og64 * 2;                     // 75.5 MB (4 slices per b)
  bool use128 = (off + og128 + 512) <= ws_size;
  char* big = alloc(use128 ? og128 : og64);
  float* Og = (float*)big;
  size_t eoff = 0;
  auto ealloc = [&](size_t bytes) -> char* {
    char* p = big + eoff; eoff = (eoff + bytes + 255) & ~(size_t)255; return p;
  };
  float* mref = (float*)ealloc((size_t)2 * 32 * L_TOT * 4);
  float* aref = (float*)ealloc((size_t)2 * 64 * L_TOT * 4);
  float* mbb  = (float*)ealloc((size_t)2 * 32 * NPIX * 4);
  float* ssq  = (float*)ealloc((size_t)2 * L_TOT * 4);
  float* invn = (float*)ealloc((size_t)2 * L_TOT * 4);

  k_convref<<<212, 256, 0, stream>>>(inref, Wm, bm, Wa, ba, ap, mref, aref);
  int n3 = 2 * 32 * NPIX;
  k_mb<<<(n3 + 255) / 256, 256, 0, stream>>>(input, Wb, bb, ap, mbb, n3);
  int ns = 2 * L_TOT + 2 * NPIX;
  k_stage1<<<(ns + 255) / 256, 256, 0, stream>>>(mref, mbb, ssq, ssqA, ns);
  k_stage2<<<(ns + 255) / 256, 256, 0, stream>>>(ssq, ssqA, invn, Mlog, ns);
  int np = N_BS + N_AIM + N_RS;
  k_pack<<<(np + 255) / 256, 256, 0, stream>>>(mref, invn, mbb, aref, Bs, Am, Rs, np);

  if (use128) {
    k_attn128<<<256, 512, 0, stream>>>(Am, Bs, Rs, Mlog, Og, Ol);
    k_inv<1><<<(2 * NPIX + 255) / 256, 256, 0, stream>>>(Ol, inv, 2 * NPIX);
    k_final<4><<<256, 512, 0, stream>>>(Og, inv, input, out);
  } else {
    k_attn64<<<256, 512, 0, stream>>>(Am, Bs, Rs, Mlog, Og, Ol);
    k_inv<0><<<(2 * NPIX + 255) / 256, 256, 0, stream>>>(Ol, inv, 2 * NPIX);
    k_final<2><<<256, 512, 0, stream>>>(Og, inv, input, out);
  }
}